// Round 14
// baseline (336.990 us; speedup 1.0000x reference)
//
#include <hip/hip_runtime.h>
#include <math.h>

#define BB 8
#define NN 512
#define CC 768
#define HH 12
#define HD 64
#define TOPK 90
#define QKV_ELEMS (BB*HH*NN*HD)   // 3145728 elements per q/k/v tensor
#define KC 2304                   // split-K: 3*768

typedef __attribute__((ext_vector_type(8))) short short8;   // 8 bf16 = 4 VGPR
typedef __attribute__((ext_vector_type(4))) float floatx4;  // MFMA C/D

__device__ inline unsigned short f2bf(float f) {
    unsigned int u = __float_as_uint(f);
    u += 0x7FFFu + ((u >> 16) & 1u);           // RNE
    return (unsigned short)(u >> 16);
}
__device__ inline float bf2f(unsigned short h) {
    return __uint_as_float(((unsigned int)h) << 16);
}

// ---------------------------------------------------------------------------
// Merged split kernel: fp32 [rows][768] -> bf16 [rows][2304], all three
// inputs in ONE launch (block-range dispatch; each range is an exact
// multiple of 256 threads x 4 elems, no bounds check needed).
// A (x):      blocks [hi | hi | lo]
// B (weights):blocks [hi | lo | hi]  (hh+hl+lh)
// ---------------------------------------------------------------------------
__global__ __launch_bounds__(256) void split_all_k(const float* __restrict__ x,
                                                   const float* __restrict__ qkv_w,
                                                   const float* __restrict__ proj_w,
                                                   unsigned short* __restrict__ Asp,
                                                   unsigned short* __restrict__ Bqkv,
                                                   unsigned short* __restrict__ Bproj) {
    const int bid = blockIdx.x;
    const float* in;
    unsigned short* o2;
    bool isA;
    int base;
    if (bid < 3072)      { in = x;      o2 = Asp;   isA = true;  base = 0; }
    else if (bid < 4800) { in = qkv_w;  o2 = Bqkv;  isA = false; base = 3072; }
    else                 { in = proj_w; o2 = Bproj; isA = false; base = 4800; }

    int idx = (bid - base) * 256 + threadIdx.x;
    int e = idx * 4;
    int m = e / CC, kk = e - m * CC;
    float4 f = *(const float4*)(in + e);
    ushort4 hi, lo;
    hi.x = f2bf(f.x); lo.x = f2bf(f.x - bf2f(hi.x));
    hi.y = f2bf(f.y); lo.y = f2bf(f.y - bf2f(hi.y));
    hi.z = f2bf(f.z); lo.z = f2bf(f.z - bf2f(hi.z));
    hi.w = f2bf(f.w); lo.w = f2bf(f.w - bf2f(hi.w));
    unsigned short* baseP = o2 + (size_t)m * KC + kk;
    *(ushort4*)(baseP)        = hi;
    *(ushort4*)(baseP + CC)   = isA ? hi : lo;
    *(ushort4*)(baseP + 2*CC) = isA ? lo : hi;
}

// ---------------------------------------------------------------------------
// 64x128-tile split-bf16 MFMA GEMM (R12/R13-verified skeleton).
// This round: 1D grid + XCD-chunked swizzle with BM-FASTEST ordering.
// Rationale: at 4-5 resident blocks/CU the whole grid is co-resident, so
// what binds is each XCD's CONCURRENT working set.  Default dispatch
// spreads all NBN B-panels over every XCD (qkv: 10.6 MB >> 4 MB L2 ->
// B thrashes to L3).  Chunking 1D ids per XCD with bm varying fastest
// makes each XCD's co-resident blocks share ~2 B-panels (1.3 MB,
// L2-resident); only A (never L2-fit) streams from L3.  R9's null was
// the OPPOSITE ordering (bn-fastest kept the full-B working set).
// wgid = (flat%8)*(nwg/8) + flat/8  (bijective; nwg%8==0);
// bn = wgid/NBM (slow), bm = wgid%NBM (fast).
// Per block: A tile 64x64 (8KB @0), B tile 128x64 (16KB @8192), 6 staging
// insts, 4 waves in 1x4 (each 64x32 out, acc[4][2], 16 MFMA/K-step).
// QKV_EPI: q,k -> split bf16 planes; v -> transposed split planes.
// Else: out + bias, NT stores.
// ---------------------------------------------------------------------------
template<bool QKV_EPI, int NBM>
__global__ __launch_bounds__(256) void gemm64(const unsigned short* __restrict__ A,
                                              const unsigned short* __restrict__ Bm,
                                              const float* __restrict__ bias,
                                              float* __restrict__ out,
                                              unsigned short* __restrict__ qh,
                                              unsigned short* __restrict__ ql,
                                              unsigned short* __restrict__ kh,
                                              unsigned short* __restrict__ kl,
                                              unsigned short* __restrict__ vth,
                                              unsigned short* __restrict__ vtl) {
    __shared__ char lds[24576];          // A 8KB @0, B 16KB @8192
    const int flat = blockIdx.x;
    const int nwg  = gridDim.x;
    const int wgid = (flat % 8) * (nwg / 8) + flat / 8;   // bijective (nwg%8==0)
    const int bn = wgid / NBM, bm = wgid % NBM;           // bm fastest in chunk
    const int tid  = threadIdx.x;
    const int wave = tid >> 6, lane = tid & 63;
    const int wn = wave;                 // 1x4 wave layout: all waves share rows
    const int quad = lane >> 4, r = lane & 15;

    // staging: 1536 chunks = 6 insts x 256 threads; c<512 -> A (rows 0..63),
    // else B (rows 0..127).  Each wave-inst (64 consecutive c) is entirely
    // A or entirely B (512 is a multiple of 64), keeping the LDS dest
    // wave-uniform-base + lane*16.
    const unsigned short* gbase[6];
#pragma unroll
    for (int i = 0; i < 6; ++i) {
        int c = tid + i*256;
        if (c < 512) {
            int m = c >> 3, octp = c & 7, oct = octp ^ (m & 7);
            gbase[i] = A + (size_t)(bm*64 + m) * KC + oct*8;
        } else {
            int c2 = c - 512;
            int m = c2 >> 3, octp = c2 & 7, oct = octp ^ (m & 7);
            gbase[i] = Bm + (size_t)(bn*128 + m) * KC + oct*8;
        }
    }

    int aoff[2][4], boff[2][2];
#pragma unroll
    for (int kb = 0; kb < 2; ++kb) {
#pragma unroll
        for (int i = 0; i < 4; ++i) {
            int ra = i*16 + r;                         // [0,64)
            aoff[kb][i] = (ra*8 + ((kb*4 + quad) ^ (ra & 7))) * 16;
        }
#pragma unroll
        for (int j = 0; j < 2; ++j) {
            int rb2 = wn*32 + j*16 + r;                // [0,128)
            boff[kb][j] = 8192 + (rb2*8 + ((kb*4 + quad) ^ (rb2 & 7))) * 16;
        }
    }

    floatx4 acc[4][2];
#pragma unroll
    for (int i = 0; i < 4; ++i)
#pragma unroll
        for (int j = 0; j < 2; ++j)
            acc[i][j] = (floatx4){0.f, 0.f, 0.f, 0.f};

    for (int it = 0; it < KC/64; ++it) {
        __syncthreads();
#pragma unroll
        for (int i = 0; i < 6; ++i) {
            __builtin_amdgcn_global_load_lds(
                (const __attribute__((address_space(1))) unsigned int*)gbase[i],
                (__attribute__((address_space(3))) unsigned int*)(lds + i*4096 + wave*1024),
                16, 0, 0);
            gbase[i] += 64;
        }
        asm volatile("s_waitcnt vmcnt(0)" ::: "memory");
        __syncthreads();

#pragma unroll
        for (int kb = 0; kb < 2; ++kb) {
            short8 af[4], bf[2];
#pragma unroll
            for (int i = 0; i < 4; ++i) af[i] = *(const short8*)(lds + aoff[kb][i]);
#pragma unroll
            for (int j = 0; j < 2; ++j) bf[j] = *(const short8*)(lds + boff[kb][j]);
#pragma unroll
            for (int i = 0; i < 4; ++i)
#pragma unroll
                for (int j = 0; j < 2; ++j)
                    acc[i][j] = __builtin_amdgcn_mfma_f32_16x16x32_bf16(af[i], bf[j], acc[i][j], 0, 0, 0);
        }
    }

    if (QKV_EPI) {
#pragma unroll
        for (int j = 0; j < 2; ++j) {
            int col = bn*128 + wn*32 + j*16 + r;       // [0,2304)
            int t = col / CC;
            int rem = col - t*CC;
            int h = rem >> 6, d = rem & 63;
            if (t == 2) {
                // v transposed split: vth/vtl[(bh*64+d)*512 + n], ushort4 over 4 rows
#pragma unroll
                for (int i = 0; i < 4; ++i) {
                    int m0 = bm*64 + i*16 + quad*4;
                    int b = m0 >> 9, n0 = m0 & 511;
                    ushort4 hi, lo;
                    hi.x = f2bf(acc[i][j][0]); lo.x = f2bf(acc[i][j][0] - bf2f(hi.x));
                    hi.y = f2bf(acc[i][j][1]); lo.y = f2bf(acc[i][j][1] - bf2f(hi.y));
                    hi.z = f2bf(acc[i][j][2]); lo.z = f2bf(acc[i][j][2] - bf2f(hi.z));
                    hi.w = f2bf(acc[i][j][3]); lo.w = f2bf(acc[i][j][3] - bf2f(hi.w));
                    size_t off = ((size_t)((b*HH + h)*HD + d))*NN + n0;
                    *(ushort4*)(vth + off) = hi;
                    *(ushort4*)(vtl + off) = lo;
                }
            } else {
                unsigned short* ph = (t == 0) ? qh : kh;
                unsigned short* pl = (t == 0) ? ql : kl;
#pragma unroll
                for (int i = 0; i < 4; ++i) {
#pragma unroll
                    for (int e = 0; e < 4; ++e) {
                        int m = bm*64 + i*16 + quad*4 + e;
                        int b = m >> 9, nrow = m & 511;
                        size_t idx = ((size_t)(b*HH + h)*NN + nrow)*HD + d;
                        float val = acc[i][j][e];
                        unsigned short hi = f2bf(val);
                        ph[idx] = hi;
                        pl[idx] = f2bf(val - bf2f(hi));
                    }
                }
            }
        }
    } else {
#pragma unroll
        for (int j = 0; j < 2; ++j) {
            int col = bn*128 + wn*32 + j*16 + r;       // [0,768)
            float bv = bias[col];
#pragma unroll
            for (int i = 0; i < 4; ++i) {
#pragma unroll
                for (int e = 0; e < 4; ++e) {
                    int m = bm*64 + i*16 + quad*4 + e; // [0,4096)
                    __builtin_nontemporal_store(acc[i][j][e] + bv,
                                                &out[(size_t)m*CC + col]);
                }
            }
        }
    }
}

// ---------------------------------------------------------------------------
// FUSED: MFMA scores + exact top-k + softmax + PV.
// Verified configuration (R8/R11/R12/R13, ~113.5-116 us attn):
//  - radix active-set top-k (all rewrites regressed; frozen)
//  - s_setprio(1) around MFMA clusters (T5, +1.5%)
//  - launch_bounds(256,2) (VGPR 116->96, cost-free)
//  - NT stores for the never-re-read attn output (FETCH 35.4->26.8 MB)
// Byte-identical this round.
// ---------------------------------------------------------------------------
__global__ __launch_bounds__(256, 2) void attn_scores_k(
        const unsigned short* __restrict__ qh, const unsigned short* __restrict__ ql,
        const unsigned short* __restrict__ kh, const unsigned short* __restrict__ kl,
        const unsigned short* __restrict__ vth, const unsigned short* __restrict__ vtl,
        const int* __restrict__ islast, float* __restrict__ attn,
        unsigned short* __restrict__ Ao) {

    __shared__ char smem[34816];
    // phase 0/1: qs = ushort[2][64][72] @0 (18432 B); ks @18432 (16384 B)
    // phase 3:   pls = ushort[64][80] @0 (10240 B); vhs @10240; vls @18432 (8192 each)
    unsigned short* qs = (unsigned short*)smem;
    char* ks = smem + 18432;

    const int bh = blockIdx.x % 96;
    const int rb = blockIdx.x / 96;
    const int tid = threadIdx.x;
    const int wv = tid >> 6, lane = tid & 63;
    const int quad = lane >> 4, r = lane & 15;
    const int b = bh / HH, h = bh % HH;

    const unsigned short* gq[2] = { qh + ((size_t)bh*NN + rb*64)*HD,
                                    ql + ((size_t)bh*NN + rb*64)*HD };
#pragma unroll
    for (int i = 0; i < 4; ++i) {
        int s = tid + i*256;
        int hl = s >> 9, s2 = s & 511;
        int row = s2 >> 3, oct = s2 & 7;
        short8 val = *(const short8*)(gq[hl] + row*HD + oct*8);
        *(short8*)&qs[(hl*64 + row)*72 + oct*8] = val;
    }
    __syncthreads();

    short8 afr[6];
    {
        const int arow = wv*16 + r;
#pragma unroll
        for (int t = 0; t < 3; ++t) {
            int src = (t == 2) ? 1 : 0;
#pragma unroll
            for (int half = 0; half < 2; ++half)
                afr[t*2+half] = *(const short8*)&qs[(src*64 + arow)*72 + half*32 + quad*8];
        }
    }

    floatx4 acc[32];
#pragma unroll
    for (int ct = 0; ct < 32; ++ct) acc[ct] = (floatx4){0.f,0.f,0.f,0.f};

    const unsigned short* gk[2] = { kh + (size_t)bh*NN*HD, kl + (size_t)bh*NN*HD };

    for (int ch = 0; ch < 8; ++ch) {
        __syncthreads();
#pragma unroll
        for (int i = 0; i < 4; ++i) {
            int s = tid + i*256;
            int hl = s >> 9, s2 = s & 511;
            int row = s2 >> 3, octp = s2 & 7;
            int oct = octp ^ (row & 7);
            const unsigned short* src = gk[hl] + (size_t)(ch*64 + row)*HD + oct*8;
            __builtin_amdgcn_global_load_lds(
                (const __attribute__((address_space(1))) unsigned int*)src,
                (__attribute__((address_space(3))) unsigned int*)(ks + (size_t)(i*256 + wv*64)*16),
                16, 0, 0);
        }
        asm volatile("s_waitcnt vmcnt(0)" ::: "memory");
        __syncthreads();

        __builtin_amdgcn_s_setprio(1);
#pragma unroll
        for (int ctl = 0; ctl < 4; ++ctl) {
            const int ct = ch*4 + ctl;
            const int n = ctl*16 + r;
#pragma unroll
            for (int t = 0; t < 3; ++t) {
                const int srcB = (t == 1) ? 1 : 0;
#pragma unroll
                for (int half = 0; half < 2; ++half) {
                    const int oct = (half*4 + quad) ^ (n & 7);
                    short8 bfr = *(const short8*)(ks + srcB*8192 + n*128 + oct*16);
                    acc[ct] = __builtin_amdgcn_mfma_f32_16x16x32_bf16(afr[t*2+half], bfr, acc[ct], 0, 0, 0);
                }
            }
        }
        __builtin_amdgcn_s_setprio(0);
    }

    const int lastv = islast[0];

    // ---- phase 2: per reg-row e: exact top-k (register radix) + softmax ----
#pragma unroll
    for (int e = 0; e < 4; ++e) {
        unsigned int key[32];
#pragma unroll
        for (int ct = 0; ct < 32; ++ct) {
            unsigned int t = __float_as_uint(acc[ct][e] * 0.125f);
            key[ct] = (t & 0x80000000u) ? ~t : (t | 0x80000000u);
        }

        unsigned int kth = 0u;
        if (!lastv) {
            unsigned int uo = key[0], ua = key[0];
#pragma unroll
            for (int ct = 1; ct < 32; ++ct) { uo |= key[ct]; ua &= key[ct]; }
#pragma unroll
            for (int off = 1; off <= 8; off <<= 1) {
                uo |= __shfl_xor(uo, off);
                ua &= __shfl_xor(ua, off);
            }
            unsigned int diff = uo ^ ua;
            int bit = 31 - __clz(diff);
            unsigned int am = 0xFFFFFFFFu;
            int kk = TOPK, cntA = 512;
            int done = (diff == 0u);
            while (__ballot(!done) != 0ull) {
                if (!done) {
                    unsigned int m1 = 0u;
#pragma unroll
                    for (int ct = 0; ct < 32; ++ct)
                        m1 |= ((key[ct] >> bit) & 1u) << ct;
                    int c1 = __popc(am & m1);
                    c1 += __shfl_xor(c1, 1);
                    c1 += __shfl_xor(c1, 2);
                    c1 += __shfl_xor(c1, 4);
                    c1 += __shfl_xor(c1, 8);
                    if (kk <= c1) { am &= m1; cntA = c1; }
                    else          { kk -= c1; am &= ~m1; cntA -= c1; }
                    --bit;
                    done = (cntA == kk) | (kk == 1) | (bit < 0);
                }
            }
            unsigned int mn = 0xFFFFFFFFu, mx = 0u;
#pragma unroll
            for (int ct = 0; ct < 32; ++ct) {
                if ((am >> ct) & 1u) {
                    mn = mn < key[ct] ? mn : key[ct];
                    mx = mx > key[ct] ? mx : key[ct];
                }
            }
#pragma unroll
            for (int off = 1; off <= 8; off <<= 1) {
                unsigned int mns = __shfl_xor(mn, off), mxs = __shfl_xor(mx, off);
                mn = mn < mns ? mn : mns; mx = mx > mxs ? mx : mxs;
            }
            kth = (kk == 1) ? mx : mn;
        }

        unsigned int umx = key[0];
#pragma unroll
        for (int ct = 1; ct < 32; ++ct) umx = umx > key[ct] ? umx : key[ct];
#pragma unroll
        for (int off = 1; off <= 8; off <<= 1) {
            unsigned int t2 = __shfl_xor(umx, off);
            umx = umx > t2 ? umx : t2;
        }
        float fmx = __uint_as_float((umx & 0x80000000u) ? (umx & 0x7FFFFFFFu) : ~umx);
        float sum = 0.f;
#pragma unroll
        for (int ct = 0; ct < 32; ++ct) {
            unsigned int uu = key[ct];
            float f = __uint_as_float((uu & 0x80000000u) ? (uu & 0x7FFFFFFFu) : ~uu);
            float ev = (lastv || uu >= kth) ? __expf(f - fmx) : 0.f;
            acc[ct][e] = ev;
            sum += ev;
        }
#pragma unroll
        for (int off = 1; off <= 8; off <<= 1) sum += __shfl_xor(sum, off);
        const float inv = 1.f / sum;
        float* arow = attn + ((size_t)bh*NN + rb*64 + wv*16 + quad*4 + e) * NN;
#pragma unroll
        for (int ct = 0; ct < 32; ++ct) {
            float p = acc[ct][e] * inv;
            acc[ct][e] = p;                  // keep normalized P in regs for PV
            __builtin_nontemporal_store(p, arow + ct*16 + r);
        }
    }

    // ---- phase 3: O = P @ V  (P in acc regs; 8 chunks of 64 K-cols) ----
    unsigned short* pls = (unsigned short*)smem;   // [64][80]
    char* vhs = smem + 10240;
    char* vls = smem + 18432;
    const unsigned short* gvh = vth + (size_t)bh*HD*NN;
    const unsigned short* gvl = vtl + (size_t)bh*HD*NN;

    floatx4 accO[4];
#pragma unroll
    for (int j = 0; j < 4; ++j) accO[j] = (floatx4){0.f,0.f,0.f,0.f};

    for (int ch = 0; ch < 8; ++ch) {
        __syncthreads();   // prev chunk reads done (first iter: phases 0-2 done)
        // write this wave's 16x64 P chunk as bf16 (C-layout -> [row][col])
#pragma unroll
        for (int ctl = 0; ctl < 4; ++ctl) {
            int col = ctl*16 + r;
#pragma unroll
            for (int e = 0; e < 4; ++e)
                pls[(wv*16 + quad*4 + e)*80 + col] = f2bf(acc[ch*4 + ctl][e]);
        }
        // stage V^T chunk (rows d=0..63, cols m=ch*64..+63), hi+lo planes
#pragma unroll
        for (int i = 0; i < 2; ++i) {
            int s = tid + i*256;
            int d = s >> 3, octp = s & 7, oct = octp ^ (d & 7);
            size_t goff = (size_t)d*NN + ch*64 + oct*8;
            __builtin_amdgcn_global_load_lds(
                (const __attribute__((address_space(1))) unsigned int*)(gvh + goff),
                (__attribute__((address_space(3))) unsigned int*)(vhs + (i*256 + wv*64)*16),
                16, 0, 0);
            __builtin_amdgcn_global_load_lds(
                (const __attribute__((address_space(1))) unsigned int*)(gvl + goff),
                (__attribute__((address_space(3))) unsigned int*)(vls + (i*256 + wv*64)*16),
                16, 0, 0);
        }
        asm volatile("s_waitcnt vmcnt(0)" ::: "memory");
        __syncthreads();

        __builtin_amdgcn_s_setprio(1);
#pragma unroll
        for (int kb = 0; kb < 2; ++kb) {
            short8 af = *(const short8*)&pls[(wv*16 + r)*80 + kb*32 + quad*8];
#pragma unroll
            for (int j = 0; j < 4; ++j) {
                int d = j*16 + r;
                int oct = (kb*4 + quad) ^ (d & 7);
                short8 bh8 = *(const short8*)(vhs + d*128 + oct*16);
                short8 bl8 = *(const short8*)(vls + d*128 + oct*16);
                accO[j] = __builtin_amdgcn_mfma_f32_16x16x32_bf16(af, bh8, accO[j], 0, 0, 0);
                accO[j] = __builtin_amdgcn_mfma_f32_16x16x32_bf16(af, bl8, accO[j], 0, 0, 0);
            }
        }
        __builtin_amdgcn_s_setprio(0);
    }

    // ---- epilogue: split-bf16 o [hi|hi|lo] into Ao ----
#pragma unroll
    for (int j = 0; j < 4; ++j) {
        int d = j*16 + r;
#pragma unroll
        for (int e = 0; e < 4; ++e) {
            int n = rb*64 + wv*16 + quad*4 + e;
            size_t mrow = (size_t)b*NN + n;
            float val = accO[j][e];
            unsigned short hi = f2bf(val);
            unsigned short lo = f2bf(val - bf2f(hi));
            unsigned short* base = Ao + mrow*KC + h*HD + d;
            base[0] = hi; base[CC] = hi; base[2*CC] = lo;
        }
    }
}

// ---------------------------------------------------------------------------
extern "C" void kernel_launch(void* const* d_in, const int* in_sizes, int n_in,
                              void* d_out, int out_size, void* d_ws, size_t ws_size,
                              hipStream_t stream) {
    const float* x      = (const float*)d_in[0];
    const float* qkv_w  = (const float*)d_in[1];
    const float* proj_w = (const float*)d_in[2];
    const float* proj_b = (const float*)d_in[3];
    const int*   islast = (const int*)d_in[4];

    float* out  = (float*)d_out;                       // [B,N,C]
    float* attn = out + (size_t)BB*NN*CC;              // [B,H,N,N]

    unsigned short* us = (unsigned short*)d_ws;
    unsigned short* vth = us;                          // [B,H,hd,N] bf16 hi
    unsigned short* vtl = vth + (size_t)QKV_ELEMS;     // [B,H,hd,N] bf16 lo
    unsigned short* qhp = vtl + (size_t)QKV_ELEMS;
    unsigned short* qlp = qhp + (size_t)QKV_ELEMS;
    unsigned short* khp = qlp + (size_t)QKV_ELEMS;
    unsigned short* klp = khp + (size_t)QKV_ELEMS;
    unsigned short* Asp   = klp + (size_t)QKV_ELEMS;   // [4096][2304]
    unsigned short* Bqkv  = Asp  + (size_t)4096*KC;    // [2304][2304]
    unsigned short* Bproj = Bqkv + (size_t)2304*KC;    // [768][2304]

    split_all_k<<<dim3(5376), 256, 0, stream>>>(x, qkv_w, proj_w, Asp, Bqkv, Bproj);

    // 1D grids, XCD-chunked bm-fastest swizzle inside (1152%8==0, 384%8==0)
    gemm64<true, 64> <<<dim3(1152), 256, 0, stream>>>(Asp, Bqkv, nullptr, nullptr,
                                                      qhp, qlp, khp, klp, vth, vtl);
    attn_scores_k    <<<dim3(96*8), 256, 0, stream>>>(qhp, qlp, khp, klp, vth, vtl,
                                                      islast, attn, Asp);
    gemm64<false, 64><<<dim3(384),  256, 0, stream>>>(Asp, Bproj, proj_b, out,
                                                      nullptr, nullptr, nullptr, nullptr,
                                                      nullptr, nullptr);
}

// Round 15
// 322.621 us; speedup vs baseline: 1.0445x; 1.0445x over previous
//
#include <hip/hip_runtime.h>
#include <math.h>

#define BB 8
#define NN 512
#define CC 768
#define HH 12
#define HD 64
#define TOPK 90
#define QKV_ELEMS (BB*HH*NN*HD)   // 3145728 elements per q/k/v tensor
#define KC 2304                   // split-K: 3*768

typedef __attribute__((ext_vector_type(8))) short short8;   // 8 bf16 = 4 VGPR
typedef __attribute__((ext_vector_type(4))) float floatx4;  // MFMA C/D

__device__ inline unsigned short f2bf(float f) {
    unsigned int u = __float_as_uint(f);
    u += 0x7FFFu + ((u >> 16) & 1u);           // RNE
    return (unsigned short)(u >> 16);
}
__device__ inline float bf2f(unsigned short h) {
    return __uint_as_float(((unsigned int)h) << 16);
}

// ---------------------------------------------------------------------------
// Merged split kernel: fp32 [rows][768] -> bf16 [rows][2304], all three
// inputs in ONE launch (block-range dispatch; each range is an exact
// multiple of 256 threads x 4 elems, no bounds check needed).
// A (x):      blocks [hi | hi | lo]
// B (weights):blocks [hi | lo | hi]  (hh+hl+lh)
// ---------------------------------------------------------------------------
__global__ __launch_bounds__(256) void split_all_k(const float* __restrict__ x,
                                                   const float* __restrict__ qkv_w,
                                                   const float* __restrict__ proj_w,
                                                   unsigned short* __restrict__ Asp,
                                                   unsigned short* __restrict__ Bqkv,
                                                   unsigned short* __restrict__ Bproj) {
    const int bid = blockIdx.x;
    const float* in;
    unsigned short* o2;
    bool isA;
    int base;
    if (bid < 3072)      { in = x;      o2 = Asp;   isA = true;  base = 0; }
    else if (bid < 4800) { in = qkv_w;  o2 = Bqkv;  isA = false; base = 3072; }
    else                 { in = proj_w; o2 = Bproj; isA = false; base = 4800; }

    int idx = (bid - base) * 256 + threadIdx.x;
    int e = idx * 4;
    int m = e / CC, kk = e - m * CC;
    float4 f = *(const float4*)(in + e);
    ushort4 hi, lo;
    hi.x = f2bf(f.x); lo.x = f2bf(f.x - bf2f(hi.x));
    hi.y = f2bf(f.y); lo.y = f2bf(f.y - bf2f(hi.y));
    hi.z = f2bf(f.z); lo.z = f2bf(f.z - bf2f(hi.z));
    hi.w = f2bf(f.w); lo.w = f2bf(f.w - bf2f(hi.w));
    unsigned short* baseP = o2 + (size_t)m * KC + kk;
    *(ushort4*)(baseP)        = hi;
    *(ushort4*)(baseP + CC)   = isA ? hi : lo;
    *(ushort4*)(baseP + 2*CC) = isA ? lo : hi;
}

// ---------------------------------------------------------------------------
// 64x128-tile split-bf16 MFMA GEMM (R12/R13-verified skeleton; FINAL).
// 2D grid, default dispatch: three swizzle experiments (R9 bn-fastest,
// R14 bm-fastest XCD-chunked, both 1D) measured neutral-to-negative on
// these grid sizes -- default order + L3 already handle the footprint.
// qkv: (64,18)=1152 blocks = 4.5/CU; proj: (64,6)=384 = 1.5/CU.  The
// 64-row tile is the occupancy fix that paid twice (R12 -6us, R13 -11us):
// more co-resident blocks hide the per-iteration vmcnt(0) drains.
// Per block: A tile 64x64 (8KB @0), B tile 128x64 (16KB @8192), 6 staging
// insts, 4 waves in 1x4 (each 64x32 out, acc[4][2], 16 MFMA/K-step).
// QKV_EPI: q,k -> split bf16 planes; v -> transposed split planes.
// Else: out + bias, NT stores (final output, never re-read on device).
// ---------------------------------------------------------------------------
template<bool QKV_EPI>
__global__ __launch_bounds__(256) void gemm64(const unsigned short* __restrict__ A,
                                              const unsigned short* __restrict__ Bm,
                                              const float* __restrict__ bias,
                                              float* __restrict__ out,
                                              unsigned short* __restrict__ qh,
                                              unsigned short* __restrict__ ql,
                                              unsigned short* __restrict__ kh,
                                              unsigned short* __restrict__ kl,
                                              unsigned short* __restrict__ vth,
                                              unsigned short* __restrict__ vtl) {
    __shared__ char lds[24576];          // A 8KB @0, B 16KB @8192
    const int bm = blockIdx.x, bn = blockIdx.y;
    const int tid  = threadIdx.x;
    const int wave = tid >> 6, lane = tid & 63;
    const int wn = wave;                 // 1x4 wave layout: all waves share rows
    const int quad = lane >> 4, r = lane & 15;

    // staging: 1536 chunks = 6 insts x 256 threads; c<512 -> A (rows 0..63),
    // else B (rows 0..127).  Each wave-inst (64 consecutive c) is entirely
    // A or entirely B (512 is a multiple of 64), keeping the LDS dest
    // wave-uniform-base + lane*16.
    const unsigned short* gbase[6];
#pragma unroll
    for (int i = 0; i < 6; ++i) {
        int c = tid + i*256;
        if (c < 512) {
            int m = c >> 3, octp = c & 7, oct = octp ^ (m & 7);
            gbase[i] = A + (size_t)(bm*64 + m) * KC + oct*8;
        } else {
            int c2 = c - 512;
            int m = c2 >> 3, octp = c2 & 7, oct = octp ^ (m & 7);
            gbase[i] = Bm + (size_t)(bn*128 + m) * KC + oct*8;
        }
    }

    int aoff[2][4], boff[2][2];
#pragma unroll
    for (int kb = 0; kb < 2; ++kb) {
#pragma unroll
        for (int i = 0; i < 4; ++i) {
            int ra = i*16 + r;                         // [0,64)
            aoff[kb][i] = (ra*8 + ((kb*4 + quad) ^ (ra & 7))) * 16;
        }
#pragma unroll
        for (int j = 0; j < 2; ++j) {
            int rb2 = wn*32 + j*16 + r;                // [0,128)
            boff[kb][j] = 8192 + (rb2*8 + ((kb*4 + quad) ^ (rb2 & 7))) * 16;
        }
    }

    floatx4 acc[4][2];
#pragma unroll
    for (int i = 0; i < 4; ++i)
#pragma unroll
        for (int j = 0; j < 2; ++j)
            acc[i][j] = (floatx4){0.f, 0.f, 0.f, 0.f};

    for (int it = 0; it < KC/64; ++it) {
        __syncthreads();
#pragma unroll
        for (int i = 0; i < 6; ++i) {
            __builtin_amdgcn_global_load_lds(
                (const __attribute__((address_space(1))) unsigned int*)gbase[i],
                (__attribute__((address_space(3))) unsigned int*)(lds + i*4096 + wave*1024),
                16, 0, 0);
            gbase[i] += 64;
        }
        asm volatile("s_waitcnt vmcnt(0)" ::: "memory");
        __syncthreads();

#pragma unroll
        for (int kb = 0; kb < 2; ++kb) {
            short8 af[4], bf[2];
#pragma unroll
            for (int i = 0; i < 4; ++i) af[i] = *(const short8*)(lds + aoff[kb][i]);
#pragma unroll
            for (int j = 0; j < 2; ++j) bf[j] = *(const short8*)(lds + boff[kb][j]);
#pragma unroll
            for (int i = 0; i < 4; ++i)
#pragma unroll
                for (int j = 0; j < 2; ++j)
                    acc[i][j] = __builtin_amdgcn_mfma_f32_16x16x32_bf16(af[i], bf[j], acc[i][j], 0, 0, 0);
        }
    }

    if (QKV_EPI) {
#pragma unroll
        for (int j = 0; j < 2; ++j) {
            int col = bn*128 + wn*32 + j*16 + r;       // [0,2304)
            int t = col / CC;
            int rem = col - t*CC;
            int h = rem >> 6, d = rem & 63;
            if (t == 2) {
                // v transposed split: vth/vtl[(bh*64+d)*512 + n], ushort4 over 4 rows
#pragma unroll
                for (int i = 0; i < 4; ++i) {
                    int m0 = bm*64 + i*16 + quad*4;
                    int b = m0 >> 9, n0 = m0 & 511;
                    ushort4 hi, lo;
                    hi.x = f2bf(acc[i][j][0]); lo.x = f2bf(acc[i][j][0] - bf2f(hi.x));
                    hi.y = f2bf(acc[i][j][1]); lo.y = f2bf(acc[i][j][1] - bf2f(hi.y));
                    hi.z = f2bf(acc[i][j][2]); lo.z = f2bf(acc[i][j][2] - bf2f(hi.z));
                    hi.w = f2bf(acc[i][j][3]); lo.w = f2bf(acc[i][j][3] - bf2f(hi.w));
                    size_t off = ((size_t)((b*HH + h)*HD + d))*NN + n0;
                    *(ushort4*)(vth + off) = hi;
                    *(ushort4*)(vtl + off) = lo;
                }
            } else {
                unsigned short* ph = (t == 0) ? qh : kh;
                unsigned short* pl = (t == 0) ? ql : kl;
#pragma unroll
                for (int i = 0; i < 4; ++i) {
#pragma unroll
                    for (int e = 0; e < 4; ++e) {
                        int m = bm*64 + i*16 + quad*4 + e;
                        int b = m >> 9, nrow = m & 511;
                        size_t idx = ((size_t)(b*HH + h)*NN + nrow)*HD + d;
                        float val = acc[i][j][e];
                        unsigned short hi = f2bf(val);
                        ph[idx] = hi;
                        pl[idx] = f2bf(val - bf2f(hi));
                    }
                }
            }
        }
    } else {
#pragma unroll
        for (int j = 0; j < 2; ++j) {
            int col = bn*128 + wn*32 + j*16 + r;       // [0,768)
            float bv = bias[col];
#pragma unroll
            for (int i = 0; i < 4; ++i) {
#pragma unroll
                for (int e = 0; e < 4; ++e) {
                    int m = bm*64 + i*16 + quad*4 + e; // [0,4096)
                    __builtin_nontemporal_store(acc[i][j][e] + bv,
                                                &out[(size_t)m*CC + col]);
                }
            }
        }
    }
}

// ---------------------------------------------------------------------------
// FUSED: MFMA scores + exact top-k + softmax + PV.
// Final verified configuration (~113.5 us):
//  - radix active-set top-k (all rewrites regressed; frozen)
//  - s_setprio(1) around MFMA clusters (T5, +1.5%)
//  - launch_bounds(256,2) (VGPR 116->96, cost-free)
//  - NT stores for the never-re-read attn output (FETCH 35.4->26.8 MB)
// Structural floor: 128 mandatory acc regs -> 2 blocks/CU -> latency-bound.
// ---------------------------------------------------------------------------
__global__ __launch_bounds__(256, 2) void attn_scores_k(
        const unsigned short* __restrict__ qh, const unsigned short* __restrict__ ql,
        const unsigned short* __restrict__ kh, const unsigned short* __restrict__ kl,
        const unsigned short* __restrict__ vth, const unsigned short* __restrict__ vtl,
        const int* __restrict__ islast, float* __restrict__ attn,
        unsigned short* __restrict__ Ao) {

    __shared__ char smem[34816];
    // phase 0/1: qs = ushort[2][64][72] @0 (18432 B); ks @18432 (16384 B)
    // phase 3:   pls = ushort[64][80] @0 (10240 B); vhs @10240; vls @18432 (8192 each)
    unsigned short* qs = (unsigned short*)smem;
    char* ks = smem + 18432;

    const int bh = blockIdx.x % 96;
    const int rb = blockIdx.x / 96;
    const int tid = threadIdx.x;
    const int wv = tid >> 6, lane = tid & 63;
    const int quad = lane >> 4, r = lane & 15;
    const int b = bh / HH, h = bh % HH;

    const unsigned short* gq[2] = { qh + ((size_t)bh*NN + rb*64)*HD,
                                    ql + ((size_t)bh*NN + rb*64)*HD };
#pragma unroll
    for (int i = 0; i < 4; ++i) {
        int s = tid + i*256;
        int hl = s >> 9, s2 = s & 511;
        int row = s2 >> 3, oct = s2 & 7;
        short8 val = *(const short8*)(gq[hl] + row*HD + oct*8);
        *(short8*)&qs[(hl*64 + row)*72 + oct*8] = val;
    }
    __syncthreads();

    short8 afr[6];
    {
        const int arow = wv*16 + r;
#pragma unroll
        for (int t = 0; t < 3; ++t) {
            int src = (t == 2) ? 1 : 0;
#pragma unroll
            for (int half = 0; half < 2; ++half)
                afr[t*2+half] = *(const short8*)&qs[(src*64 + arow)*72 + half*32 + quad*8];
        }
    }

    floatx4 acc[32];
#pragma unroll
    for (int ct = 0; ct < 32; ++ct) acc[ct] = (floatx4){0.f,0.f,0.f,0.f};

    const unsigned short* gk[2] = { kh + (size_t)bh*NN*HD, kl + (size_t)bh*NN*HD };

    for (int ch = 0; ch < 8; ++ch) {
        __syncthreads();
#pragma unroll
        for (int i = 0; i < 4; ++i) {
            int s = tid + i*256;
            int hl = s >> 9, s2 = s & 511;
            int row = s2 >> 3, octp = s2 & 7;
            int oct = octp ^ (row & 7);
            const unsigned short* src = gk[hl] + (size_t)(ch*64 + row)*HD + oct*8;
            __builtin_amdgcn_global_load_lds(
                (const __attribute__((address_space(1))) unsigned int*)src,
                (__attribute__((address_space(3))) unsigned int*)(ks + (size_t)(i*256 + wv*64)*16),
                16, 0, 0);
        }
        asm volatile("s_waitcnt vmcnt(0)" ::: "memory");
        __syncthreads();

        __builtin_amdgcn_s_setprio(1);
#pragma unroll
        for (int ctl = 0; ctl < 4; ++ctl) {
            const int ct = ch*4 + ctl;
            const int n = ctl*16 + r;
#pragma unroll
            for (int t = 0; t < 3; ++t) {
                const int srcB = (t == 1) ? 1 : 0;
#pragma unroll
                for (int half = 0; half < 2; ++half) {
                    const int oct = (half*4 + quad) ^ (n & 7);
                    short8 bfr = *(const short8*)(ks + srcB*8192 + n*128 + oct*16);
                    acc[ct] = __builtin_amdgcn_mfma_f32_16x16x32_bf16(afr[t*2+half], bfr, acc[ct], 0, 0, 0);
                }
            }
        }
        __builtin_amdgcn_s_setprio(0);
    }

    const int lastv = islast[0];

    // ---- phase 2: per reg-row e: exact top-k (register radix) + softmax ----
#pragma unroll
    for (int e = 0; e < 4; ++e) {
        unsigned int key[32];
#pragma unroll
        for (int ct = 0; ct < 32; ++ct) {
            unsigned int t = __float_as_uint(acc[ct][e] * 0.125f);
            key[ct] = (t & 0x80000000u) ? ~t : (t | 0x80000000u);
        }

        unsigned int kth = 0u;
        if (!lastv) {
            unsigned int uo = key[0], ua = key[0];
#pragma unroll
            for (int ct = 1; ct < 32; ++ct) { uo |= key[ct]; ua &= key[ct]; }
#pragma unroll
            for (int off = 1; off <= 8; off <<= 1) {
                uo |= __shfl_xor(uo, off);
                ua &= __shfl_xor(ua, off);
            }
            unsigned int diff = uo ^ ua;
            int bit = 31 - __clz(diff);
            unsigned int am = 0xFFFFFFFFu;
            int kk = TOPK, cntA = 512;
            int done = (diff == 0u);
            while (__ballot(!done) != 0ull) {
                if (!done) {
                    unsigned int m1 = 0u;
#pragma unroll
                    for (int ct = 0; ct < 32; ++ct)
                        m1 |= ((key[ct] >> bit) & 1u) << ct;
                    int c1 = __popc(am & m1);
                    c1 += __shfl_xor(c1, 1);
                    c1 += __shfl_xor(c1, 2);
                    c1 += __shfl_xor(c1, 4);
                    c1 += __shfl_xor(c1, 8);
                    if (kk <= c1) { am &= m1; cntA = c1; }
                    else          { kk -= c1; am &= ~m1; cntA -= c1; }
                    --bit;
                    done = (cntA == kk) | (kk == 1) | (bit < 0);
                }
            }
            unsigned int mn = 0xFFFFFFFFu, mx = 0u;
#pragma unroll
            for (int ct = 0; ct < 32; ++ct) {
                if ((am >> ct) & 1u) {
                    mn = mn < key[ct] ? mn : key[ct];
                    mx = mx > key[ct] ? mx : key[ct];
                }
            }
#pragma unroll
            for (int off = 1; off <= 8; off <<= 1) {
                unsigned int mns = __shfl_xor(mn, off), mxs = __shfl_xor(mx, off);
                mn = mn < mns ? mn : mns; mx = mx > mxs ? mx : mxs;
            }
            kth = (kk == 1) ? mx : mn;
        }

        unsigned int umx = key[0];
#pragma unroll
        for (int ct = 1; ct < 32; ++ct) umx = umx > key[ct] ? umx : key[ct];
#pragma unroll
        for (int off = 1; off <= 8; off <<= 1) {
            unsigned int t2 = __shfl_xor(umx, off);
            umx = umx > t2 ? umx : t2;
        }
        float fmx = __uint_as_float((umx & 0x80000000u) ? (umx & 0x7FFFFFFFu) : ~umx);
        float sum = 0.f;
#pragma unroll
        for (int ct = 0; ct < 32; ++ct) {
            unsigned int uu = key[ct];
            float f = __uint_as_float((uu & 0x80000000u) ? (uu & 0x7FFFFFFFu) : ~uu);
            float ev = (lastv || uu >= kth) ? __expf(f - fmx) : 0.f;
            acc[ct][e] = ev;
            sum += ev;
        }
#pragma unroll
        for (int off = 1; off <= 8; off <<= 1) sum += __shfl_xor(sum, off);
        const float inv = 1.f / sum;
        float* arow = attn + ((size_t)bh*NN + rb*64 + wv*16 + quad*4 + e) * NN;
#pragma unroll
        for (int ct = 0; ct < 32; ++ct) {
            float p = acc[ct][e] * inv;
            acc[ct][e] = p;                  // keep normalized P in regs for PV
            __builtin_nontemporal_store(p, arow + ct*16 + r);
        }
    }

    // ---- phase 3: O = P @ V  (P in acc regs; 8 chunks of 64 K-cols) ----
    unsigned short* pls = (unsigned short*)smem;   // [64][80]
    char* vhs = smem + 10240;
    char* vls = smem + 18432;
    const unsigned short* gvh = vth + (size_t)bh*HD*NN;
    const unsigned short* gvl = vtl + (size_t)bh*HD*NN;

    floatx4 accO[4];
#pragma unroll
    for (int j = 0; j < 4; ++j) accO[j] = (floatx4){0.f,0.f,0.f,0.f};

    for (int ch = 0; ch < 8; ++ch) {
        __syncthreads();   // prev chunk reads done (first iter: phases 0-2 done)
        // write this wave's 16x64 P chunk as bf16 (C-layout -> [row][col])
#pragma unroll
        for (int ctl = 0; ctl < 4; ++ctl) {
            int col = ctl*16 + r;
#pragma unroll
            for (int e = 0; e < 4; ++e)
                pls[(wv*16 + quad*4 + e)*80 + col] = f2bf(acc[ch*4 + ctl][e]);
        }
        // stage V^T chunk (rows d=0..63, cols m=ch*64..+63), hi+lo planes
#pragma unroll
        for (int i = 0; i < 2; ++i) {
            int s = tid + i*256;
            int d = s >> 3, octp = s & 7, oct = octp ^ (d & 7);
            size_t goff = (size_t)d*NN + ch*64 + oct*8;
            __builtin_amdgcn_global_load_lds(
                (const __attribute__((address_space(1))) unsigned int*)(gvh + goff),
                (__attribute__((address_space(3))) unsigned int*)(vhs + (i*256 + wv*64)*16),
                16, 0, 0);
            __builtin_amdgcn_global_load_lds(
                (const __attribute__((address_space(1))) unsigned int*)(gvl + goff),
                (__attribute__((address_space(3))) unsigned int*)(vls + (i*256 + wv*64)*16),
                16, 0, 0);
        }
        asm volatile("s_waitcnt vmcnt(0)" ::: "memory");
        __syncthreads();

        __builtin_amdgcn_s_setprio(1);
#pragma unroll
        for (int kb = 0; kb < 2; ++kb) {
            short8 af = *(const short8*)&pls[(wv*16 + r)*80 + kb*32 + quad*8];
#pragma unroll
            for (int j = 0; j < 4; ++j) {
                int d = j*16 + r;
                int oct = (kb*4 + quad) ^ (d & 7);
                short8 bh8 = *(const short8*)(vhs + d*128 + oct*16);
                short8 bl8 = *(const short8*)(vls + d*128 + oct*16);
                accO[j] = __builtin_amdgcn_mfma_f32_16x16x32_bf16(af, bh8, accO[j], 0, 0, 0);
                accO[j] = __builtin_amdgcn_mfma_f32_16x16x32_bf16(af, bl8, accO[j], 0, 0, 0);
            }
        }
        __builtin_amdgcn_s_setprio(0);
    }

    // ---- epilogue: split-bf16 o [hi|hi|lo] into Ao ----
#pragma unroll
    for (int j = 0; j < 4; ++j) {
        int d = j*16 + r;
#pragma unroll
        for (int e = 0; e < 4; ++e) {
            int n = rb*64 + wv*16 + quad*4 + e;
            size_t mrow = (size_t)b*NN + n;
            float val = accO[j][e];
            unsigned short hi = f2bf(val);
            unsigned short lo = f2bf(val - bf2f(hi));
            unsigned short* base = Ao + mrow*KC + h*HD + d;
            base[0] = hi; base[CC] = hi; base[2*CC] = lo;
        }
    }
}

// ---------------------------------------------------------------------------
extern "C" void kernel_launch(void* const* d_in, const int* in_sizes, int n_in,
                              void* d_out, int out_size, void* d_ws, size_t ws_size,
                              hipStream_t stream) {
    const float* x      = (const float*)d_in[0];
    const float* qkv_w  = (const float*)d_in[1];
    const float* proj_w = (const float*)d_in[2];
    const float* proj_b = (const float*)d_in[3];
    const int*   islast = (const int*)d_in[4];

    float* out  = (float*)d_out;                       // [B,N,C]
    float* attn = out + (size_t)BB*NN*CC;              // [B,H,N,N]

    unsigned short* us = (unsigned short*)d_ws;
    unsigned short* vth = us;                          // [B,H,hd,N] bf16 hi
    unsigned short* vtl = vth + (size_t)QKV_ELEMS;     // [B,H,hd,N] bf16 lo
    unsigned short* qhp = vtl + (size_t)QKV_ELEMS;
    unsigned short* qlp = qhp + (size_t)QKV_ELEMS;
    unsigned short* khp = qlp + (size_t)QKV_ELEMS;
    unsigned short* klp = khp + (size_t)QKV_ELEMS;
    unsigned short* Asp   = klp + (size_t)QKV_ELEMS;   // [4096][2304]
    unsigned short* Bqkv  = Asp  + (size_t)4096*KC;    // [2304][2304]
    unsigned short* Bproj = Bqkv + (size_t)2304*KC;    // [768][2304]

    split_all_k<<<dim3(5376), 256, 0, stream>>>(x, qkv_w, proj_w, Asp, Bqkv, Bproj);

    gemm64<true> <<<dim3(64, 18), 256, 0, stream>>>(Asp, Bqkv, nullptr, nullptr,
                                                    qhp, qlp, khp, klp, vth, vtl);
    attn_scores_k<<<dim3(96*8),   256, 0, stream>>>(qhp, qlp, khp, klp, vth, vtl,
                                                    islast, attn, Asp);
    gemm64<false><<<dim3(64, 6),  256, 0, stream>>>(Asp, Bproj, proj_b, out,
                                                    nullptr, nullptr, nullptr, nullptr,
                                                    nullptr, nullptr);
}